// Round 4
// baseline (24.721 us; speedup 1.0000x reference)
//
#include <hip/hip_runtime.h>

#define NOUT 10
#define SIG_DIM 584   // 8 + 64 + 512

__device__ __forceinline__ float rdlane(float x, int lane) {
    return __int_as_float(__builtin_amdgcn_readlane(__float_as_int(x), lane));
}

// One block = one batch element. 4 waves = 4 time-chunks of 32 increments
// (dX row 127 zeroed so all chunks are 32 steps). Lane l=(i,j): i=l>>3, j=l&7.
// Per-lane chunk state: S3[i][j][0..7], S2[i][j], S1[i], S1[j].
// Row broadcast via v_readlane of prepass registers (lane 2s: row s cols 0-3,
// lane 2s+1: cols 4-7) -- no LDS traffic for rows.
// Handoff: ALL waves publish to s_sig[w]; barrier; ALL waves fold all 4 chunks
// from the zero state (symmetric, no early return -- r3's replay-divergence
// surface removed). Epilogue split across waves.
__global__ __launch_bounds__(256, 4) void sig_linear_kernel(
    const float* __restrict__ X, const float* __restrict__ W,
    const float* __restrict__ bias, float* __restrict__ out)
{
    __shared__ __align__(16) float s_path[1024];        // 128 x 8
    __shared__ __align__(16) float s_dx[1024];          // 128 x 8, row 127 = 0
    __shared__ __align__(16) float s_sig[4 * SIG_DIM];  // 4 chunk signatures

    const int tid = threadIdx.x;
    const int w = tid >> 6;
    const int l = tid & 63;
    const int i = l >> 3;
    const int j = l & 7;
    const int b = blockIdx.x;

    // Stage the whole path (4 KB), coalesced.
    const float4* Xb4 = reinterpret_cast<const float4*>(X + (size_t)b * 1024);
    reinterpret_cast<float4*>(s_path)[tid] = Xb4[tid];
    __syncthreads();

    // dX prepass: lane l of wave w computes dX floats [w*256+l*4, +4).
    const int idx = w * 256 + l * 4;
    const bool v = idx < 1016;                 // 127*8 valid dX floats
    float4 d4;
    {
        const float4 a  = *reinterpret_cast<const float4*>(s_path + idx);
        const float4 c4 = *reinterpret_cast<const float4*>(s_path + (v ? idx + 8 : idx));
        d4.x = v ? (c4.x - a.x) : 0.f;
        d4.y = v ? (c4.y - a.y) : 0.f;
        d4.z = v ? (c4.z - a.z) : 0.f;
        d4.w = v ? (c4.w - a.w) : 0.f;
        *reinterpret_cast<float4*>(s_dx + idx) = d4;
    }
    __syncthreads();   // cross-lane dX reads below need a real barrier

    float s3[8];
#pragma unroll
    for (int k = 0; k < 8; ++k) s3[k] = 0.f;
    float s2 = 0.f, s1i = 0.f, s1j = 0.f;

    const float* dxb = s_dx + w * 256;
#pragma unroll
    for (int s = 0; s < 32; ++s) {
        const float dxi = dxb[s * 8 + i];      // ds_read_b32, 8-addr broadcast
        const float dxj = dxb[s * 8 + j];
        const float k0 = rdlane(d4.x, 2 * s);
        const float k1 = rdlane(d4.y, 2 * s);
        const float k2 = rdlane(d4.z, 2 * s);
        const float k3 = rdlane(d4.w, 2 * s);
        const float k4 = rdlane(d4.x, 2 * s + 1);
        const float k5 = rdlane(d4.y, 2 * s + 1);
        const float k6 = rdlane(d4.z, 2 * s + 1);
        const float k7 = rdlane(d4.w, 2 * s + 1);
        const float c = dxi * dxj;
        const float u = s1i * dxj;
        const float f = fmaf(0.5f, u, fmaf(1.0f / 6.0f, c, s2));
        s3[0] = fmaf(f, k0, s3[0]);
        s3[1] = fmaf(f, k1, s3[1]);
        s3[2] = fmaf(f, k2, s3[2]);
        s3[3] = fmaf(f, k3, s3[3]);
        s3[4] = fmaf(f, k4, s3[4]);
        s3[5] = fmaf(f, k5, s3[5]);
        s3[6] = fmaf(f, k6, s3[6]);
        s3[7] = fmaf(f, k7, s3[7]);
        s2 = fmaf(0.5f, c, s2 + u);
        s1i += dxi;
        s1j += dxj;
    }

    // ALL waves publish their chunk signature to s_sig[w].
    {
        float* sg = s_sig + w * SIG_DIM;
        if (i == 0) sg[j] = s1j;               // lanes (0,j) hold S1[j]
        sg[8 + l] = s2;
        *reinterpret_cast<float4*>(sg + 72 + l * 8) =
            make_float4(s3[0], s3[1], s3[2], s3[3]);
        *reinterpret_cast<float4*>(sg + 72 + l * 8 + 4) =
            make_float4(s3[4], s3[5], s3[6], s3[7]);
    }
    __syncthreads();

    // ALL waves redundantly fold chunks 0..3 from the zero state.
    //   S3 += S2a[ij]*S1b[k] + S1a[i]*S2b[jk] + S3b[ijk]
    //   S2 += S1a[i]*S1b[j] + S2b[ij];  S1 += S1b
#pragma unroll
    for (int k = 0; k < 8; ++k) s3[k] = 0.f;
    s2 = 0.f; s1i = 0.f; s1j = 0.f;
#pragma unroll
    for (int c = 0; c < 4; ++c) {
        const float* sg = s_sig + c * SIG_DIM;
        const float4 b0 = *reinterpret_cast<const float4*>(sg);      // S1b[0..3]
        const float4 b1 = *reinterpret_cast<const float4*>(sg + 4);  // S1b[4..7]
        const float s1bi = sg[i];
        const float s1bj = sg[j];
        const float s2b = sg[8 + l];
        const float4 q0 = *reinterpret_cast<const float4*>(sg + 8 + j * 8);
        const float4 q1 = *reinterpret_cast<const float4*>(sg + 8 + j * 8 + 4);
        const float4 t0 = *reinterpret_cast<const float4*>(sg + 72 + l * 8);
        const float4 t1 = *reinterpret_cast<const float4*>(sg + 72 + l * 8 + 4);
        s3[0] = fmaf(s2, b0.x, fmaf(s1i, q0.x, s3[0] + t0.x));
        s3[1] = fmaf(s2, b0.y, fmaf(s1i, q0.y, s3[1] + t0.y));
        s3[2] = fmaf(s2, b0.z, fmaf(s1i, q0.z, s3[2] + t0.z));
        s3[3] = fmaf(s2, b0.w, fmaf(s1i, q0.w, s3[3] + t0.w));
        s3[4] = fmaf(s2, b1.x, fmaf(s1i, q1.x, s3[4] + t1.x));
        s3[5] = fmaf(s2, b1.y, fmaf(s1i, q1.y, s3[5] + t1.y));
        s3[6] = fmaf(s2, b1.z, fmaf(s1i, q1.z, s3[6] + t1.z));
        s3[7] = fmaf(s2, b1.w, fmaf(s1i, q1.w, s3[7] + t1.w));
        s2 = s2 + fmaf(s1i, s1bj, s2b);
        s1i += s1bi;
        s1j += s1bj;
    }

    // Epilogue split across waves: wave w handles o = w, w+4, w+8.
    for (int o = w; o < NOUT; o += 4) {
        const float* wrow = W + o * SIG_DIM;
        float part = s2 * wrow[8 + l];
        const float4 w0 = *reinterpret_cast<const float4*>(wrow + 72 + l * 8);
        const float4 w1 = *reinterpret_cast<const float4*>(wrow + 72 + l * 8 + 4);
        part = fmaf(s3[0], w0.x, part); part = fmaf(s3[1], w0.y, part);
        part = fmaf(s3[2], w0.z, part); part = fmaf(s3[3], w0.w, part);
        part = fmaf(s3[4], w1.x, part); part = fmaf(s3[5], w1.y, part);
        part = fmaf(s3[6], w1.z, part); part = fmaf(s3[7], w1.w, part);
        if (i == 0) part = fmaf(s1j, wrow[j], part);   // S1 contribution
#pragma unroll
        for (int off = 32; off > 0; off >>= 1) part += __shfl_xor(part, off);
        if (l == 0) out[b * NOUT + o] = part + bias[o];
    }
}

extern "C" void kernel_launch(void* const* d_in, const int* in_sizes, int n_in,
                              void* d_out, int out_size, void* d_ws, size_t ws_size,
                              hipStream_t stream) {
    const float* X = (const float*)d_in[0];     // (2048, 128, 8)
    const float* W = (const float*)d_in[1];     // (10, 584)
    const float* bias = (const float*)d_in[2];  // (10,)
    float* out = (float*)d_out;                 // (2048, 10)
    sig_linear_kernel<<<dim3(2048), dim3(256), 0, stream>>>(X, W, bias, out);
}

// Round 5
// 21.602 us; speedup vs baseline: 1.1443x; 1.1443x over previous
//
#include <hip/hip_runtime.h>

#define NOUT 10
#define SIG_DIM 584   // 8 + 64 + 512
#define TPAD 132      // padded T-stride: (i*TPAD)%32 = 4i -> conflict-free cols

__device__ __forceinline__ float rdlane(float x, int lane) {
    return __int_as_float(__builtin_amdgcn_readlane(__float_as_int(x), lane));
}

// 4 waves/block, ONE batch element per wave (512 blocks; 2 waves/SIMD).
// Full 127-step serial recurrence per wave -- no chunk fold, no s_sig.
// Lane l=(i,j): i=l>>3, j=l&7. State: S3[i][j][0..7], S2[i][j], S1[i], S1[j].
// Row broadcast: v_readlane from prepass regs dQ (lane 2s: row s cols 0-3,
// lane 2s+1: cols 4-7, s = row within 32-row q-section) -- zero LDS traffic.
// Per-lane dxi/dxj: transposed padded LDS columns, one b128 per 4 steps.
__global__ __launch_bounds__(256) void sig_linear_kernel(
    const float* __restrict__ X, const float* __restrict__ W,
    const float* __restrict__ bias, float* __restrict__ out)
{
    __shared__ float s_dxT[4][8 * TPAD];   // per-wave transposed dX (16.9 KB)

    const int tid = threadIdx.x;
    const int w = tid >> 6;
    const int l = tid & 63;
    const int i = l >> 3;
    const int j = l & 7;
    const int b = blockIdx.x * 4 + w;

    const float* Xb = X + (size_t)b * 1024;
    float* dxT = &s_dxT[w][0];
    const int cb = (l & 1) * 4;            // this lane's 4-col segment
    const int rl = l >> 1;                 // row within q-section

    // Prepass: dX rows q*32+rl into regs dA..dD (for readlane) and transposed
    // into LDS (for per-lane column reads). Global loads are lane-coalesced.
    float4 dA, dB, dC, dD;
#define PREP(DQ, QQ)                                                          \
    {                                                                         \
        const int r = (QQ) * 32 + rl;                                         \
        const float* xr = Xb + r * 8 + cb;                                    \
        const float4 a  = *reinterpret_cast<const float4*>(xr);               \
        const float4 c4 = *reinterpret_cast<const float4*>(xr + (r < 127 ? 8 : 0)); \
        DQ.x = (r < 127) ? c4.x - a.x : 0.f;                                  \
        DQ.y = (r < 127) ? c4.y - a.y : 0.f;                                  \
        DQ.z = (r < 127) ? c4.z - a.z : 0.f;                                  \
        DQ.w = (r < 127) ? c4.w - a.w : 0.f;                                  \
        dxT[(cb + 0) * TPAD + r] = DQ.x;                                      \
        dxT[(cb + 1) * TPAD + r] = DQ.y;                                      \
        dxT[(cb + 2) * TPAD + r] = DQ.z;                                      \
        dxT[(cb + 3) * TPAD + r] = DQ.w;                                      \
    }
    PREP(dA, 0) PREP(dB, 1) PREP(dC, 2) PREP(dD, 3)
#undef PREP
    __syncthreads();   // cross-lane LDS reads below need a real barrier

    float s3[8];
#pragma unroll
    for (int k = 0; k < 8; ++k) s3[k] = 0.f;
    float s2 = 0.f, s1i = 0.f, s1j = 0.f;

    const float* icol = dxT + i * TPAD;    // conflict-free: banks 4i+t
    const float* jcol = dxT + j * TPAD;

#define STEP(DQ, LB, DXI, DXJ)                                                \
    {                                                                         \
        const float k0 = rdlane(DQ.x, (LB));                                  \
        const float k1 = rdlane(DQ.y, (LB));                                  \
        const float k2 = rdlane(DQ.z, (LB));                                  \
        const float k3 = rdlane(DQ.w, (LB));                                  \
        const float k4 = rdlane(DQ.x, (LB) + 1);                              \
        const float k5 = rdlane(DQ.y, (LB) + 1);                              \
        const float k6 = rdlane(DQ.z, (LB) + 1);                              \
        const float k7 = rdlane(DQ.w, (LB) + 1);                              \
        const float cc = (DXI) * (DXJ);                                       \
        const float uu = s1i * (DXJ);                                         \
        const float f  = fmaf(0.5f, uu, fmaf(1.0f / 6.0f, cc, s2));           \
        s3[0] = fmaf(f, k0, s3[0]);                                           \
        s3[1] = fmaf(f, k1, s3[1]);                                           \
        s3[2] = fmaf(f, k2, s3[2]);                                           \
        s3[3] = fmaf(f, k3, s3[3]);                                           \
        s3[4] = fmaf(f, k4, s3[4]);                                           \
        s3[5] = fmaf(f, k5, s3[5]);                                           \
        s3[6] = fmaf(f, k6, s3[6]);                                           \
        s3[7] = fmaf(f, k7, s3[7]);                                           \
        s2 = fmaf(0.5f, cc, s2 + uu);                                         \
        s1i += (DXI);                                                         \
        s1j += (DXJ);                                                         \
    }

    // One q-section: 32 rows, 8 groups of 4 steps; readlane base = g*8.
#define SECTION(DQ, QQ)                                                       \
    for (int g = 0; g < 8; ++g) {                                             \
        const int t0 = (QQ) * 32 + g * 4;                                     \
        const float4 ic = *reinterpret_cast<const float4*>(icol + t0);        \
        const float4 jc = *reinterpret_cast<const float4*>(jcol + t0);        \
        const int lb = g * 8;                                                 \
        STEP(DQ, lb + 0, ic.x, jc.x)                                          \
        STEP(DQ, lb + 2, ic.y, jc.y)                                          \
        STEP(DQ, lb + 4, ic.z, jc.z)                                          \
        STEP(DQ, lb + 6, ic.w, jc.w)                                          \
    }
    SECTION(dA, 0)
    SECTION(dB, 1)
    SECTION(dC, 2)
    SECTION(dD, 3)
#undef SECTION
#undef STEP

    // Epilogue (r1-proven): out[b][o] = bias[o] + W[o][:] . sig[b][:]
    // sig layout: [0..7]=S1, [8+l]=S2[i][j], [72+l*8+k]=S3[i][j][k]
#pragma unroll
    for (int o = 0; o < NOUT; ++o) {
        const float* wrow = W + o * SIG_DIM;
        float part = s2 * wrow[8 + l];
        const float4 w0 = *reinterpret_cast<const float4*>(wrow + 72 + l * 8);
        const float4 w1 = *reinterpret_cast<const float4*>(wrow + 72 + l * 8 + 4);
        part = fmaf(s3[0], w0.x, part); part = fmaf(s3[1], w0.y, part);
        part = fmaf(s3[2], w0.z, part); part = fmaf(s3[3], w0.w, part);
        part = fmaf(s3[4], w1.x, part); part = fmaf(s3[5], w1.y, part);
        part = fmaf(s3[6], w1.z, part); part = fmaf(s3[7], w1.w, part);
        if (i == 0) part = fmaf(s1j, wrow[j], part);   // S1 contribution
#pragma unroll
        for (int off = 32; off > 0; off >>= 1) part += __shfl_xor(part, off);
        if (l == 0) out[b * NOUT + o] = part + bias[o];
    }
}

extern "C" void kernel_launch(void* const* d_in, const int* in_sizes, int n_in,
                              void* d_out, int out_size, void* d_ws, size_t ws_size,
                              hipStream_t stream) {
    const float* X = (const float*)d_in[0];     // (2048, 128, 8)
    const float* W = (const float*)d_in[1];     // (10, 584)
    const float* bias = (const float*)d_in[2];  // (10,)
    float* out = (float*)d_out;                 // (2048, 10)
    sig_linear_kernel<<<dim3(512), dim3(256), 0, stream>>>(X, W, bias, out);
}